// Round 5
// baseline (596.470 us; speedup 1.0000x reference)
//
#include <hip/hip_runtime.h>
#include <math.h>

#define N_NODES 8192
#define FIN 256
#define HDIM 128
#define FOUTD 16
#define KSEL 4096
#define CAP 128   // max row degree capacity (Binom mean ~64, sd ~8; 128 = +8 sd)

typedef unsigned int uint;
typedef unsigned short ushort;

static __device__ __forceinline__ ushort f2bf(float f) {
    uint u = __float_as_uint(f);
    return (ushort)((u + 0x7FFFu + ((u >> 16) & 1u)) >> 16);   // RNE, no NaN expected
}
static __device__ __forceinline__ float bf_lo(uint u) { return __uint_as_float(u << 16); }
static __device__ __forceinline__ float bf_hi(uint u) { return __uint_as_float(u & 0xFFFF0000u); }

// ---------------- fused: upper-triangle CSR scan (LDS compaction) + gemm0
// Row i scans only j > i (A symmetric, zero diag): 128 MB instead of 256 MB.
// LDS counter per row (R4-proven); the R3 disaster was 64-lane same-address
// GLOBAL atomics — LDS same-address atomics are cheap.
// grid = 512 groups x 17 blocks: 16 CSR rows + 1 gemm block interleaved.
__global__ __launch_bounds__(256) void csru_gemm0(const float* __restrict__ A,
                                                  int* __restrict__ cols,
                                                  int* __restrict__ degU,
                                                  int* __restrict__ degT,
                                                  const float* __restrict__ x,
                                                  const float* __restrict__ W0,
                                                  const float* __restrict__ b0,
                                                  float* __restrict__ T0) {
    int grp = blockIdx.x / 17;
    int rem = blockIdx.x - grp * 17;
    if (rem < 16) {
        int i = grp * 16 + rem;
        __shared__ int cnt;
        __shared__ int scols[CAP];
        if (threadIdx.x == 0) cnt = 0;
        __syncthreads();
        const float4* Arow = (const float4*)(A + (size_t)i * N_NODES);
        for (int c4 = (i >> 2) + threadIdx.x; c4 < N_NODES / 4; c4 += 256) {
            float4 v = Arow[c4];
            int base = c4 * 4;
            if (v.x != 0.0f && base + 0 > i) { int p = atomicAdd(&cnt, 1); if (p < CAP) scols[p] = base; }
            if (v.y != 0.0f && base + 1 > i) { int p = atomicAdd(&cnt, 1); if (p < CAP) scols[p] = base + 1; }
            if (v.z != 0.0f && base + 2 > i) { int p = atomicAdd(&cnt, 1); if (p < CAP) scols[p] = base + 2; }
            if (v.w != 0.0f && base + 3 > i) { int p = atomicAdd(&cnt, 1); if (p < CAP) scols[p] = base + 3; }
        }
        __syncthreads();
        int c = cnt; if (c > CAP) c = CAP;
        for (int t = threadIdx.x; t < c; t += 256)
            cols[(size_t)i * CAP + t] = scols[t];
        if (threadIdx.x == 0) { degU[i] = c; degT[i] = c; }
    } else {
        // ---- gemm0: 16 rows of t0 = x@W0 + b0 (two 128-thread halves x 8 rows)
        int half = threadIdx.x >> 7;
        int tid = threadIdx.x & 127;
        int row0 = grp * 16 + half * 8;
        float acc[8];
#pragma unroll
        for (int r = 0; r < 8; r++) acc[r] = 0.0f;
        const float* Xb = x + (size_t)row0 * FIN;
        for (int k = 0; k < FIN; k += 4) {
            float w0 = W0[(k + 0) * HDIM + tid];
            float w1 = W0[(k + 1) * HDIM + tid];
            float w2 = W0[(k + 2) * HDIM + tid];
            float w3 = W0[(k + 3) * HDIM + tid];
#pragma unroll
            for (int r = 0; r < 8; r++) {
                const float* xr = Xb + r * FIN + k;   // wave-uniform -> scalar loads
                acc[r] = fmaf(xr[0], w0, acc[r]);
                acc[r] = fmaf(xr[1], w1, acc[r]);
                acc[r] = fmaf(xr[2], w2, acc[r]);
                acc[r] = fmaf(xr[3], w3, acc[r]);
            }
        }
        float bias = b0[tid];
#pragma unroll
        for (int r = 0; r < 8; r++)
            T0[(size_t)(row0 + r) * HDIM + tid] = acc[r] + bias;
    }
}

// ---------------- mirror pass: append (j,i) for every upper edge (i,j).
// Distinct-address atomics per lane (0.26M total over 8192 counters).
// Appends land at positions >= degU[j]; readers of upper lists read < degU[j]
// -> no overlap. After this kernel degT[] = total degree.
__global__ __launch_bounds__(256) void csr_mirror(int* __restrict__ cols,
                                                  const int* __restrict__ degU,
                                                  int* __restrict__ degT) {
    int wv = threadIdx.x >> 6, lane = threadIdx.x & 63;
    int i = blockIdx.x * 4 + wv;
    int du = degU[i];
    for (int t = lane; t < du; t += 64) {
        int j = cols[(size_t)i * CAP + t];
        int pos = atomicAdd(&degT[j], 1);
        if (pos < CAP) cols[(size_t)j * CAP + pos] = i;
    }
}

// ------------- spmm over full graph (fp32) + score + fused P1 = h0@W1 (bf16)
// one wave per row; lane owns features {2lane, 2lane+1}.
// t1 = (h0*g)@W1 + b1 == g[row]*P1[row] + b1 (per-row gating commutes with
// the GEMM) -> gemm1 stage eliminated, H0 never materialized.
__global__ __launch_bounds__(128) void spmm_score_p1(const float* __restrict__ T0,
                                                     const int* __restrict__ cols,
                                                     const int* __restrict__ degT,
                                                     const float* __restrict__ pw,
                                                     const float* __restrict__ pb,
                                                     const float* __restrict__ W1,
                                                     uint* __restrict__ P1u,
                                                     float* __restrict__ sraw) {
    int wv = threadIdx.x >> 6, lane = threadIdx.x & 63;
    int row = blockIdx.x * 2 + wv;
    const float2* T2p = (const float2*)T0;
    const int* cl = cols + (size_t)row * CAP;
    int d = degT[row]; if (d > CAP) d = CAP;
    float2 a0 = {0.f, 0.f}, a1 = {0.f, 0.f}, a2 = {0.f, 0.f}, a3 = {0.f, 0.f};
    int j = 0;
    for (; j + 4 <= d; j += 4) {
        int c0 = cl[j], c1 = cl[j + 1], c2 = cl[j + 2], c3 = cl[j + 3];
        float2 v0 = T2p[(size_t)c0 * 64 + lane];
        float2 v1 = T2p[(size_t)c1 * 64 + lane];
        float2 v2 = T2p[(size_t)c2 * 64 + lane];
        float2 v3 = T2p[(size_t)c3 * 64 + lane];
        a0.x += v0.x; a0.y += v0.y;
        a1.x += v1.x; a1.y += v1.y;
        a2.x += v2.x; a2.y += v2.y;
        a3.x += v3.x; a3.y += v3.y;
    }
    for (; j < d; j++) {
        float2 v0 = T2p[(size_t)cl[j] * 64 + lane];
        a0.x += v0.x; a0.y += v0.y;
    }
    float2 own = T2p[(size_t)row * 64 + lane];
    float inv = 1.0f / (float)(1 + d);
    float hx = fmaxf((own.x + (a0.x + a1.x) + (a2.x + a3.x)) * inv, 0.f);
    float hy = fmaxf((own.y + (a0.y + a1.y) + (a2.y + a3.y)) * inv, 0.f);
    // score (fp32-exact selection path)
    float2 pw2 = ((const float2*)pw)[lane];
    float v = hx * pw2.x + hy * pw2.y;
    for (int off = 32; off; off >>= 1) v += __shfl_down(v, off);
    if (lane == 0) sraw[row] = v + pb[0];
    // P1 row-GEMV: p1[2l,2l+1] = sum_k h0[k] * W1[k][2l,2l+1]
    float accx = 0.f, accy = 0.f;
    const float2* W1r = (const float2*)W1;
#pragma unroll 4
    for (int kk = 0; kk < 64; kk++) {
        float xk0 = __uint_as_float(__builtin_amdgcn_readlane(__float_as_uint(hx), kk));
        float xk1 = __uint_as_float(__builtin_amdgcn_readlane(__float_as_uint(hy), kk));
        float2 w0 = W1r[(size_t)(2 * kk) * 64 + lane];
        float2 w1 = W1r[(size_t)(2 * kk + 1) * 64 + lane];
        accx = fmaf(xk0, w0.x, accx); accy = fmaf(xk0, w0.y, accy);
        accx = fmaf(xk1, w1.x, accx); accy = fmaf(xk1, w1.y, accy);
    }
    P1u[(size_t)row * 64 + lane] = (uint)f2bf(accx) | ((uint)f2bf(accy) << 16);
}

// ---------------------- top-k (4096 of 8192) via 4-pass 8-bit radix select
__global__ __launch_bounds__(256) void topk_radix(const float* __restrict__ sraw,
                                                  int* __restrict__ sel,
                                                  float* __restrict__ g) {
    int tid = threadIdx.x;
    int lane = tid & 63, wv = tid >> 6;
    float v[32];
    unsigned key[32];
    float ss = 0.f;
#pragma unroll
    for (int e = 0; e < 32; e++) {
        float x = sraw[tid * 32 + e];
        v[e] = x; ss += x * x;
        unsigned b = __float_as_uint(x);
        key[e] = (b & 0x80000000u) ? ~b : (b | 0x80000000u);
    }
    __shared__ float fr[4];
    for (int off = 32; off; off >>= 1) ss += __shfl_down(ss, off);
    if (lane == 0) fr[wv] = ss;
    __syncthreads();
    float inv_norm = 1.0f / sqrtf(fr[0] + fr[1] + fr[2] + fr[3]);

    __shared__ int hist[256];
    __shared__ int wred[4];
    __shared__ int bd, bkneed;
    unsigned prefix = 0; int kneed = KSEL;
    for (int pass = 0; pass < 4; pass++) {
        int shift = 24 - 8 * pass;
        unsigned maskAbove = (pass == 0) ? 0u : (0xFFFFFFFFu << (shift + 8));
        hist[tid] = 0;
        __syncthreads();
#pragma unroll
        for (int e = 0; e < 32; e++)
            if ((key[e] & maskAbove) == prefix)
                atomicAdd(&hist[(key[e] >> shift) & 255], 1);
        __syncthreads();
        int h = hist[tid];
        int s = h;
#pragma unroll
        for (int off = 1; off < 64; off <<= 1) {
            int t = __shfl_down(s, off);
            if (lane + off < 64) s += t;
        }
        if (lane == 0) wred[wv] = s;
        __syncthreads();
        int addhi = 0;
        for (int w = wv + 1; w < 4; w++) addhi += wred[w];
        int s_here = s + addhi;            // keys in bins >= tid
        int s_next = s_here - h;           // keys in bins >  tid
        if (s_here >= kneed && s_next < kneed) { bd = tid; bkneed = kneed - s_next; }
        __syncthreads();
        prefix |= ((unsigned)bd) << shift;
        kneed = bkneed;
        __syncthreads();
    }
    unsigned T = prefix;
    int eq = 0;
#pragma unroll
    for (int e = 0; e < 32; e++) eq += (key[e] == T);
    int p = eq;
#pragma unroll
    for (int off = 1; off < 64; off <<= 1) {
        int t = __shfl_up(p, off);
        if (lane >= off) p += t;
    }
    __shared__ int wpre[4];
    if (lane == 63) wpre[wv] = p;
    __syncthreads();
    int base = 0;
    for (int w = 0; w < wv; w++) base += wpre[w];
    int excl = base + p - eq;
    int seen = 0;
#pragma unroll
    for (int e = 0; e < 32; e++) {
        int i = tid * 32 + e;
        int s2;
        if (key[e] > T) s2 = 1;
        else if (key[e] == T) { s2 = (excl + seen < kneed) ? 1 : 0; seen++; }
        else s2 = 0;
        sel[i] = s2;
        g[i] = s2 ? (1.0f / (1.0f + expf(-(v[e] * inv_norm)))) : 0.0f;
    }
}

// -------- fused: pooled spmm over g.P1+b1 (bf16) -> xu -> t2 = xu@Wu+bu (bf16)
__global__ __launch_bounds__(64) void pool_gemm(const uint* __restrict__ P1u,
                                                const int* __restrict__ cols,
                                                const int* __restrict__ degT,
                                                const int* __restrict__ sel,
                                                const float* __restrict__ g,
                                                const float* __restrict__ b1,
                                                const float* __restrict__ Wu,
                                                const float* __restrict__ bu,
                                                uint* __restrict__ T2u) {
    int row = blockIdx.x;
    int t = threadIdx.x;   // owns features/cols 2t, 2t+1
    float2 biasU = ((const float2*)bu)[t];
    if (!sel[row]) {   // xu row = 0 -> t2 = bu
        T2u[(size_t)row * 64 + t] = (uint)f2bf(biasU.x) | ((uint)f2bf(biasU.y) << 16);
        return;
    }
    const int* cl = cols + (size_t)row * CAP;
    int d = degT[row]; if (d > CAP) d = CAP;
    // sum of t1 over {row} u selected nbrs; t1[c] = g[c]*P1[c] + b1, and the
    // (cnt+1)*b1 term divided by (1+cnt) is exactly b1 -> add b1 after avg.
    uint su = P1u[(size_t)row * 64 + t];
    float grow = g[row];
    float ax = bf_lo(su) * grow, ay = bf_hi(su) * grow;
    int cnt = 0;
    for (int j = 0; j < d; j++) {
        int c = cl[j];
        if (sel[c]) {
            cnt++;
            uint u = P1u[(size_t)c * 64 + t];
            float gc = g[c];
            ax = fmaf(bf_lo(u), gc, ax); ay = fmaf(bf_hi(u), gc, ay);
        }
    }
    float2 b1p = ((const float2*)b1)[t];
    float inv = 1.0f / (float)(1 + cnt);
    float xux = fmaxf(fmaf(ax, inv, b1p.x), 0.f);
    float xuy = fmaxf(fmaf(ay, inv, b1p.y), 0.f);
    float accx = biasU.x, accy = biasU.y;
    const float2* Wur = (const float2*)Wu;   // [128][64] pairs
#pragma unroll 4
    for (int kk = 0; kk < 64; kk++) {
        float xk0 = __uint_as_float(__builtin_amdgcn_readlane(__float_as_uint(xux), kk));
        float xk1 = __uint_as_float(__builtin_amdgcn_readlane(__float_as_uint(xuy), kk));
        float2 w0 = Wur[(size_t)(2 * kk) * 64 + t];
        float2 w1 = Wur[(size_t)(2 * kk + 1) * 64 + t];
        accx = fmaf(xk0, w0.x, accx); accy = fmaf(xk0, w0.y, accy);
        accx = fmaf(xk1, w1.x, accx); accy = fmaf(xk1, w1.y, accy);
    }
    T2u[(size_t)row * 64 + t] = (uint)f2bf(accx) | ((uint)f2bf(accy) << 16);
}

// -------- fused: full spmm over T2(bf16) -> hu -> t3 = hu@Wf+bf (fp32, F=16)
__global__ __launch_bounds__(64) void up_gemm16(const uint* __restrict__ T2u,
                                                const int* __restrict__ cols,
                                                const int* __restrict__ degT,
                                                const float* __restrict__ Wf,
                                                const float* __restrict__ bf_,
                                                float* __restrict__ T3) {
    int row = blockIdx.x;
    int t = threadIdx.x;
    const int* cl = cols + (size_t)row * CAP;
    int d = degT[row]; if (d > CAP) d = CAP;
    uint su = T2u[(size_t)row * 64 + t];
    float ax = bf_lo(su), ay = bf_hi(su);
    for (int j = 0; j < d; j++) {
        uint u = T2u[(size_t)cl[j] * 64 + t];
        ax += bf_lo(u); ay += bf_hi(u);
    }
    float inv = 1.0f / (float)(1 + d);
    float hux = fmaxf(ax * inv, 0.f);
    float huy = fmaxf(ay * inv, 0.f);
    __shared__ float hs[128];
    hs[2 * t] = hux; hs[2 * t + 1] = huy;
    __syncthreads();
    int c = t & 15, gg = t >> 4;   // 4 k-groups x 16 cols
    float p = 0.f;
#pragma unroll 8
    for (int kk = 0; kk < 32; kk++) {
        int k = gg * 32 + kk;
        p = fmaf(hs[k], Wf[k * FOUTD + c], p);
    }
    p += __shfl_xor(p, 16);
    p += __shfl_xor(p, 32);
    if (t < 16) T3[(size_t)row * FOUTD + t] = p + bf_[t];
}

// ---------------------- final: spmm F=16 + log_softmax
__global__ __launch_bounds__(64) void spmm16_lsm(const float* __restrict__ T3,
                                                 const int* __restrict__ cols,
                                                 const int* __restrict__ degT,
                                                 float* __restrict__ out) {
    int lane = threadIdx.x;          // 64 = 4 rows x 16 cols
    int r = lane >> 4, c = lane & 15;
    int row = blockIdx.x * 4 + r;
    const int* cl = cols + (size_t)row * CAP;
    int d = degT[row]; if (d > CAP) d = CAP;
    float acc = T3[(size_t)row * FOUTD + c];
    for (int j = 0; j < d; j++) acc += T3[(size_t)cl[j] * FOUTD + c];
    float v = acc / (float)(1 + d);
    float m = v;
    for (int off = 1; off < 16; off <<= 1) m = fmaxf(m, __shfl_xor(m, off, 16));
    float e = expf(v - m);
    float s = e;
    for (int off = 1; off < 16; off <<= 1) s += __shfl_xor(s, off, 16);
    out[(size_t)row * FOUTD + c] = v - m - logf(s);
}

// ------------------------------------------------------------------ launch
extern "C" void kernel_launch(void* const* d_in, const int* in_sizes, int n_in,
                              void* d_out, int out_size, void* d_ws, size_t ws_size,
                              hipStream_t stream) {
    const float* x  = (const float*)d_in[0];
    const float* A  = (const float*)d_in[1];
    const float* W0 = (const float*)d_in[2];
    const float* b0 = (const float*)d_in[3];
    const float* W1 = (const float*)d_in[4];
    const float* b1 = (const float*)d_in[5];
    const float* pw = (const float*)d_in[6];
    const float* pb = (const float*)d_in[7];
    const float* Wu = (const float*)d_in[8];
    const float* bu = (const float*)d_in[9];
    const float* Wf = (const float*)d_in[10];
    const float* bf = (const float*)d_in[11];
    float* out = (float*)d_out;

    char* ws = (char*)d_ws;
    const size_t MB = 1024 * 1024;
    int*   cols = (int*)  (ws);                    // 4 MB
    int*   degU = (int*)  (ws + 4 * MB);           // 32 KB
    int*   degT = (int*)  (ws + 4 * MB + 65536);   // 32 KB
    float* T0   = (float*)(ws + 5  * MB);          // 4 MB fp32
    uint*  P1   = (uint*) (ws + 9  * MB);          // 2 MB bf16
    uint*  T2   = (uint*) (ws + 11 * MB);          // 2 MB bf16
    float* T3   = (float*)(ws + 13 * MB);          // 512 KB fp32
    float* sraw = (float*)(ws + 14 * MB);          // 32 KB
    int*   sel  = (int*)  (ws + 14 * MB + 65536);  // 32 KB
    float* g    = (float*)(ws + 14 * MB + 131072); // 32 KB

    // 1. upper-triangle CSR (LDS compaction)  ||  t0 = x@W0+b0
    csru_gemm0<<<512 * 17, 256, 0, stream>>>(A, cols, degU, degT, x, W0, b0, T0);
    // 2. mirror lower edges; degT becomes total degree
    csr_mirror<<<N_NODES / 4, 256, 0, stream>>>(cols, degU, degT);
    // 3. h0 = relu(norm_adj(A)@t0); raw score; P1 = h0@W1 (bf16)
    spmm_score_p1<<<N_NODES / 2, 128, 0, stream>>>(T0, cols, degT, pw, pb, W1, P1, sraw);
    // 4. top-k radix select -> sel, g
    topk_radix<<<1, 256, 0, stream>>>(sraw, sel, g);
    // 5. xu = scatter(relu(norm_adj(Ap)@(g.P1+b1))); t2 = xu@Wu + bu (bf16)
    pool_gemm<<<N_NODES, 64, 0, stream>>>(P1, cols, degT, sel, g, b1, Wu, bu, T2);
    // 6. hu = relu(norm_adj(A)@t2); t3 = hu@Wf + bf (fp32)
    up_gemm16<<<N_NODES, 64, 0, stream>>>(T2, cols, degT, Wf, bf, T3);
    // 7. hf = norm_adj(A)@t3; out = log_softmax(hf)
    spmm16_lsm<<<N_NODES / 4, 64, 0, stream>>>(T3, cols, degT, out);
}

// Round 6
// 583.409 us; speedup vs baseline: 1.0224x; 1.0224x over previous
//
#include <hip/hip_runtime.h>
#include <math.h>

#define N_NODES 8192
#define FIN 256
#define HDIM 128
#define FOUTD 16
#define KSEL 4096
#define CAP 128   // per-list capacity (max total degree ~95)

typedef unsigned int uint;
typedef unsigned short ushort;

static __device__ __forceinline__ ushort f2bf(float f) {
    uint u = __float_as_uint(f);
    return (ushort)((u + 0x7FFFu + ((u >> 16) & 1u)) >> 16);   // RNE, no NaN expected
}
static __device__ __forceinline__ float bf_lo(uint u) { return __uint_as_float(u << 16); }
static __device__ __forceinline__ float bf_hi(uint u) { return __uint_as_float(u & 0xFFFF0000u); }

// ---------------- fused: balanced upper-triangle CSR + inline mirror + gemm0
// Pair (p, 8191-p): combined upper-scan length is 8192 entries for EVERY block
// (R5's per-row scan was imbalanced -> critical path never shrank).
// Mirror edges append to a DISJOINT region (cols2/cnt2) with distinct-address
// global atomics (~32 hits/counter, time-spread) -> no separate mirror kernel.
// grid = 512 groups x 9 blocks: 8 pair-blocks + 1 gemm block interleaved.
__global__ __launch_bounds__(256) void csrp_gemm0(const float* __restrict__ A,
                                                  int* __restrict__ cols,
                                                  int* __restrict__ cols2,
                                                  int* __restrict__ degU,
                                                  int* __restrict__ cnt2,
                                                  const float* __restrict__ x,
                                                  const float* __restrict__ W0,
                                                  const float* __restrict__ b0,
                                                  float* __restrict__ T0) {
    int grp = blockIdx.x / 9;
    int rem = blockIdx.x - grp * 9;
    if (rem < 8) {
        int p  = grp * 8 + rem;          // 0..4095
        int ra = p, rb = N_NODES - 1 - p;
        __shared__ int cA, cB;
        __shared__ int sA[CAP], sB[CAP];
        if (threadIdx.x == 0) { cA = 0; cB = 0; }
        __syncthreads();
        const float4* Ar = (const float4*)(A + (size_t)ra * N_NODES);
        for (int c4 = (ra >> 2) + threadIdx.x; c4 < N_NODES / 4; c4 += 256) {
            float4 v = Ar[c4];
            int base = c4 * 4;
            if (v.x != 0.0f && base + 0 > ra) { int q = atomicAdd(&cA, 1); if (q < CAP) sA[q] = base; }
            if (v.y != 0.0f && base + 1 > ra) { int q = atomicAdd(&cA, 1); if (q < CAP) sA[q] = base + 1; }
            if (v.z != 0.0f && base + 2 > ra) { int q = atomicAdd(&cA, 1); if (q < CAP) sA[q] = base + 2; }
            if (v.w != 0.0f && base + 3 > ra) { int q = atomicAdd(&cA, 1); if (q < CAP) sA[q] = base + 3; }
        }
        const float4* Br = (const float4*)(A + (size_t)rb * N_NODES);
        for (int c4 = (rb >> 2) + threadIdx.x; c4 < N_NODES / 4; c4 += 256) {
            float4 v = Br[c4];
            int base = c4 * 4;
            if (v.x != 0.0f && base + 0 > rb) { int q = atomicAdd(&cB, 1); if (q < CAP) sB[q] = base; }
            if (v.y != 0.0f && base + 1 > rb) { int q = atomicAdd(&cB, 1); if (q < CAP) sB[q] = base + 1; }
            if (v.z != 0.0f && base + 2 > rb) { int q = atomicAdd(&cB, 1); if (q < CAP) sB[q] = base + 2; }
            if (v.w != 0.0f && base + 3 > rb) { int q = atomicAdd(&cB, 1); if (q < CAP) sB[q] = base + 3; }
        }
        __syncthreads();
        int dA = cA; if (dA > CAP) dA = CAP;
        int dB = cB; if (dB > CAP) dB = CAP;
        for (int t = threadIdx.x; t < dA; t += 256) {
            int j = sA[t];
            cols[(size_t)ra * CAP + t] = j;
            int pos = atomicAdd(&cnt2[j], 1);
            if (pos < CAP) cols2[(size_t)j * CAP + pos] = ra;
        }
        for (int t = threadIdx.x; t < dB; t += 256) {
            int j = sB[t];
            cols[(size_t)rb * CAP + t] = j;
            int pos = atomicAdd(&cnt2[j], 1);
            if (pos < CAP) cols2[(size_t)j * CAP + pos] = rb;
        }
        if (threadIdx.x == 0) { degU[ra] = dA; degU[rb] = dB; }
    } else {
        // ---- gemm0: 16 rows of t0 = x@W0 + b0 (two 128-thread halves x 8 rows)
        int half = threadIdx.x >> 7;
        int tid = threadIdx.x & 127;
        int row0 = grp * 16 + half * 8;
        float acc[8];
#pragma unroll
        for (int r = 0; r < 8; r++) acc[r] = 0.0f;
        const float* Xb = x + (size_t)row0 * FIN;
        for (int k = 0; k < FIN; k += 4) {
            float w0 = W0[(k + 0) * HDIM + tid];
            float w1 = W0[(k + 1) * HDIM + tid];
            float w2 = W0[(k + 2) * HDIM + tid];
            float w3 = W0[(k + 3) * HDIM + tid];
#pragma unroll
            for (int r = 0; r < 8; r++) {
                const float* xr = Xb + r * FIN + k;   // wave-uniform -> scalar loads
                acc[r] = fmaf(xr[0], w0, acc[r]);
                acc[r] = fmaf(xr[1], w1, acc[r]);
                acc[r] = fmaf(xr[2], w2, acc[r]);
                acc[r] = fmaf(xr[3], w3, acc[r]);
            }
        }
        float bias = b0[tid];
#pragma unroll
        for (int r = 0; r < 8; r++)
            T0[(size_t)(row0 + r) * HDIM + tid] = acc[r] + bias;
    }
}

// ------------- spmm over full graph (fp32) + score + fused P1 = h0@W1 (bf16)
// one wave per row; lane owns features {2lane, 2lane+1}. Row's neighbor set =
// upper list (cols/degU) + mirror list (cols2/cnt2).
__global__ __launch_bounds__(128) void spmm_score_p1(const float* __restrict__ T0,
                                                     const int* __restrict__ cols,
                                                     const int* __restrict__ cols2,
                                                     const int* __restrict__ degU,
                                                     const int* __restrict__ cnt2,
                                                     const float* __restrict__ pw,
                                                     const float* __restrict__ pb,
                                                     const float* __restrict__ W1,
                                                     uint* __restrict__ P1u,
                                                     float* __restrict__ sraw) {
    int wv = threadIdx.x >> 6, lane = threadIdx.x & 63;
    int row = blockIdx.x * 2 + wv;
    const float2* T2p = (const float2*)T0;
    int dU = degU[row]; if (dU > CAP) dU = CAP;
    int dM = cnt2[row]; if (dM > CAP) dM = CAP;
    float2 a0 = {0.f, 0.f}, a1 = {0.f, 0.f}, a2 = {0.f, 0.f}, a3 = {0.f, 0.f};
    for (int part = 0; part < 2; part++) {
        const int* cl = (part ? cols2 : cols) + (size_t)row * CAP;
        int d = part ? dM : dU;
        int j = 0;
        for (; j + 4 <= d; j += 4) {
            int c0 = cl[j], c1 = cl[j + 1], c2 = cl[j + 2], c3 = cl[j + 3];
            float2 v0 = T2p[(size_t)c0 * 64 + lane];
            float2 v1 = T2p[(size_t)c1 * 64 + lane];
            float2 v2 = T2p[(size_t)c2 * 64 + lane];
            float2 v3 = T2p[(size_t)c3 * 64 + lane];
            a0.x += v0.x; a0.y += v0.y;
            a1.x += v1.x; a1.y += v1.y;
            a2.x += v2.x; a2.y += v2.y;
            a3.x += v3.x; a3.y += v3.y;
        }
        for (; j < d; j++) {
            float2 v0 = T2p[(size_t)cl[j] * 64 + lane];
            a0.x += v0.x; a0.y += v0.y;
        }
    }
    int d = dU + dM;
    float2 own = T2p[(size_t)row * 64 + lane];
    float inv = 1.0f / (float)(1 + d);
    float hx = fmaxf((own.x + (a0.x + a1.x) + (a2.x + a3.x)) * inv, 0.f);
    float hy = fmaxf((own.y + (a0.y + a1.y) + (a2.y + a3.y)) * inv, 0.f);
    // score (fp32-exact selection path)
    float2 pw2 = ((const float2*)pw)[lane];
    float v = hx * pw2.x + hy * pw2.y;
    for (int off = 32; off; off >>= 1) v += __shfl_down(v, off);
    if (lane == 0) sraw[row] = v + pb[0];
    // P1 row-GEMV: p1[2l,2l+1] = sum_k h0[k] * W1[k][2l,2l+1]
    float accx = 0.f, accy = 0.f;
    const float2* W1r = (const float2*)W1;
#pragma unroll 4
    for (int kk = 0; kk < 64; kk++) {
        float xk0 = __uint_as_float(__builtin_amdgcn_readlane(__float_as_uint(hx), kk));
        float xk1 = __uint_as_float(__builtin_amdgcn_readlane(__float_as_uint(hy), kk));
        float2 w0 = W1r[(size_t)(2 * kk) * 64 + lane];
        float2 w1 = W1r[(size_t)(2 * kk + 1) * 64 + lane];
        accx = fmaf(xk0, w0.x, accx); accy = fmaf(xk0, w0.y, accy);
        accx = fmaf(xk1, w1.x, accx); accy = fmaf(xk1, w1.y, accy);
    }
    P1u[(size_t)row * 64 + lane] = (uint)f2bf(accx) | ((uint)f2bf(accy) << 16);
}

// ---------------------- top-k (4096 of 8192) via 4-pass 8-bit radix select
__global__ __launch_bounds__(256) void topk_radix(const float* __restrict__ sraw,
                                                  int* __restrict__ sel,
                                                  float* __restrict__ g) {
    int tid = threadIdx.x;
    int lane = tid & 63, wv = tid >> 6;
    float v[32];
    unsigned key[32];
    float ss = 0.f;
#pragma unroll
    for (int e = 0; e < 32; e++) {
        float x = sraw[tid * 32 + e];
        v[e] = x; ss += x * x;
        unsigned b = __float_as_uint(x);
        key[e] = (b & 0x80000000u) ? ~b : (b | 0x80000000u);
    }
    __shared__ float fr[4];
    for (int off = 32; off; off >>= 1) ss += __shfl_down(ss, off);
    if (lane == 0) fr[wv] = ss;
    __syncthreads();
    float inv_norm = 1.0f / sqrtf(fr[0] + fr[1] + fr[2] + fr[3]);

    __shared__ int hist[256];
    __shared__ int wred[4];
    __shared__ int bd, bkneed;
    unsigned prefix = 0; int kneed = KSEL;
    for (int pass = 0; pass < 4; pass++) {
        int shift = 24 - 8 * pass;
        unsigned maskAbove = (pass == 0) ? 0u : (0xFFFFFFFFu << (shift + 8));
        hist[tid] = 0;
        __syncthreads();
#pragma unroll
        for (int e = 0; e < 32; e++)
            if ((key[e] & maskAbove) == prefix)
                atomicAdd(&hist[(key[e] >> shift) & 255], 1);
        __syncthreads();
        int h = hist[tid];
        int s = h;
#pragma unroll
        for (int off = 1; off < 64; off <<= 1) {
            int t = __shfl_down(s, off);
            if (lane + off < 64) s += t;
        }
        if (lane == 0) wred[wv] = s;
        __syncthreads();
        int addhi = 0;
        for (int w = wv + 1; w < 4; w++) addhi += wred[w];
        int s_here = s + addhi;            // keys in bins >= tid
        int s_next = s_here - h;           // keys in bins >  tid
        if (s_here >= kneed && s_next < kneed) { bd = tid; bkneed = kneed - s_next; }
        __syncthreads();
        prefix |= ((unsigned)bd) << shift;
        kneed = bkneed;
        __syncthreads();
    }
    unsigned T = prefix;
    int eq = 0;
#pragma unroll
    for (int e = 0; e < 32; e++) eq += (key[e] == T);
    int p = eq;
#pragma unroll
    for (int off = 1; off < 64; off <<= 1) {
        int t = __shfl_up(p, off);
        if (lane >= off) p += t;
    }
    __shared__ int wpre[4];
    if (lane == 63) wpre[wv] = p;
    __syncthreads();
    int base = 0;
    for (int w = 0; w < wv; w++) base += wpre[w];
    int excl = base + p - eq;
    int seen = 0;
#pragma unroll
    for (int e = 0; e < 32; e++) {
        int i = tid * 32 + e;
        int s2;
        if (key[e] > T) s2 = 1;
        else if (key[e] == T) { s2 = (excl + seen < kneed) ? 1 : 0; seen++; }
        else s2 = 0;
        sel[i] = s2;
        g[i] = s2 ? (1.0f / (1.0f + expf(-(v[e] * inv_norm)))) : 0.0f;
    }
}

// -------- fused: pooled spmm over g.P1+b1 (bf16) -> xu -> t2 = xu@Wu+bu (bf16)
__global__ __launch_bounds__(64) void pool_gemm(const uint* __restrict__ P1u,
                                                const int* __restrict__ cols,
                                                const int* __restrict__ cols2,
                                                const int* __restrict__ degU,
                                                const int* __restrict__ cnt2,
                                                const int* __restrict__ sel,
                                                const float* __restrict__ g,
                                                const float* __restrict__ b1,
                                                const float* __restrict__ Wu,
                                                const float* __restrict__ bu,
                                                uint* __restrict__ T2u) {
    int row = blockIdx.x;
    int t = threadIdx.x;   // owns features/cols 2t, 2t+1
    float2 biasU = ((const float2*)bu)[t];
    if (!sel[row]) {   // xu row = 0 -> t2 = bu
        T2u[(size_t)row * 64 + t] = (uint)f2bf(biasU.x) | ((uint)f2bf(biasU.y) << 16);
        return;
    }
    // t1[c] = g[c]*P1[c] + b1; the (cnt+1)*b1 term / (1+cnt) is exactly b1.
    uint su = P1u[(size_t)row * 64 + t];
    float grow = g[row];
    float ax = bf_lo(su) * grow, ay = bf_hi(su) * grow;
    int cnt = 0;
    int dU = degU[row]; if (dU > CAP) dU = CAP;
    int dM = cnt2[row]; if (dM > CAP) dM = CAP;
    for (int part = 0; part < 2; part++) {
        const int* cl = (part ? cols2 : cols) + (size_t)row * CAP;
        int d = part ? dM : dU;
        for (int j = 0; j < d; j++) {
            int c = cl[j];
            if (sel[c]) {
                cnt++;
                uint u = P1u[(size_t)c * 64 + t];
                float gc = g[c];
                ax = fmaf(bf_lo(u), gc, ax); ay = fmaf(bf_hi(u), gc, ay);
            }
        }
    }
    float2 b1p = ((const float2*)b1)[t];
    float inv = 1.0f / (float)(1 + cnt);
    float xux = fmaxf(fmaf(ax, inv, b1p.x), 0.f);
    float xuy = fmaxf(fmaf(ay, inv, b1p.y), 0.f);
    float accx = biasU.x, accy = biasU.y;
    const float2* Wur = (const float2*)Wu;   // [128][64] pairs
#pragma unroll 4
    for (int kk = 0; kk < 64; kk++) {
        float xk0 = __uint_as_float(__builtin_amdgcn_readlane(__float_as_uint(xux), kk));
        float xk1 = __uint_as_float(__builtin_amdgcn_readlane(__float_as_uint(xuy), kk));
        float2 w0 = Wur[(size_t)(2 * kk) * 64 + t];
        float2 w1 = Wur[(size_t)(2 * kk + 1) * 64 + t];
        accx = fmaf(xk0, w0.x, accx); accy = fmaf(xk0, w0.y, accy);
        accx = fmaf(xk1, w1.x, accx); accy = fmaf(xk1, w1.y, accy);
    }
    T2u[(size_t)row * 64 + t] = (uint)f2bf(accx) | ((uint)f2bf(accy) << 16);
}

// -------- fused: full spmm over T2(bf16) -> hu -> t3 = hu@Wf+bf (fp32, F=16)
__global__ __launch_bounds__(64) void up_gemm16(const uint* __restrict__ T2u,
                                                const int* __restrict__ cols,
                                                const int* __restrict__ cols2,
                                                const int* __restrict__ degU,
                                                const int* __restrict__ cnt2,
                                                const float* __restrict__ Wf,
                                                const float* __restrict__ bf_,
                                                float* __restrict__ T3) {
    int row = blockIdx.x;
    int t = threadIdx.x;
    uint su = T2u[(size_t)row * 64 + t];
    float ax = bf_lo(su), ay = bf_hi(su);
    int dU = degU[row]; if (dU > CAP) dU = CAP;
    int dM = cnt2[row]; if (dM > CAP) dM = CAP;
    for (int part = 0; part < 2; part++) {
        const int* cl = (part ? cols2 : cols) + (size_t)row * CAP;
        int d = part ? dM : dU;
        for (int j = 0; j < d; j++) {
            uint u = T2u[(size_t)cl[j] * 64 + t];
            ax += bf_lo(u); ay += bf_hi(u);
        }
    }
    int d = dU + dM;
    float inv = 1.0f / (float)(1 + d);
    float hux = fmaxf(ax * inv, 0.f);
    float huy = fmaxf(ay * inv, 0.f);
    __shared__ float hs[128];
    hs[2 * t] = hux; hs[2 * t + 1] = huy;
    __syncthreads();
    int c = t & 15, gg = t >> 4;   // 4 k-groups x 16 cols
    float p = 0.f;
#pragma unroll 8
    for (int kk = 0; kk < 32; kk++) {
        int k = gg * 32 + kk;
        p = fmaf(hs[k], Wf[k * FOUTD + c], p);
    }
    p += __shfl_xor(p, 16);
    p += __shfl_xor(p, 32);
    if (t < 16) T3[(size_t)row * FOUTD + t] = p + bf_[t];
}

// ---------------------- final: spmm F=16 + log_softmax
__global__ __launch_bounds__(64) void spmm16_lsm(const float* __restrict__ T3,
                                                 const int* __restrict__ cols,
                                                 const int* __restrict__ cols2,
                                                 const int* __restrict__ degU,
                                                 const int* __restrict__ cnt2,
                                                 float* __restrict__ out) {
    int lane = threadIdx.x;          // 64 = 4 rows x 16 cols
    int r = lane >> 4, c = lane & 15;
    int row = blockIdx.x * 4 + r;
    float acc = T3[(size_t)row * FOUTD + c];
    int dU = degU[row]; if (dU > CAP) dU = CAP;
    int dM = cnt2[row]; if (dM > CAP) dM = CAP;
    for (int part = 0; part < 2; part++) {
        const int* cl = (part ? cols2 : cols) + (size_t)row * CAP;
        int d = part ? dM : dU;
        for (int j = 0; j < d; j++) acc += T3[(size_t)cl[j] * FOUTD + c];
    }
    int d = dU + dM;
    float v = acc / (float)(1 + d);
    float m = v;
    for (int off = 1; off < 16; off <<= 1) m = fmaxf(m, __shfl_xor(m, off, 16));
    float e = expf(v - m);
    float s = e;
    for (int off = 1; off < 16; off <<= 1) s += __shfl_xor(s, off, 16);
    out[(size_t)row * FOUTD + c] = v - m - logf(s);
}

// ------------------------------------------------------------------ launch
extern "C" void kernel_launch(void* const* d_in, const int* in_sizes, int n_in,
                              void* d_out, int out_size, void* d_ws, size_t ws_size,
                              hipStream_t stream) {
    const float* x  = (const float*)d_in[0];
    const float* A  = (const float*)d_in[1];
    const float* W0 = (const float*)d_in[2];
    const float* b0 = (const float*)d_in[3];
    const float* W1 = (const float*)d_in[4];
    const float* b1 = (const float*)d_in[5];
    const float* pw = (const float*)d_in[6];
    const float* pb = (const float*)d_in[7];
    const float* Wu = (const float*)d_in[8];
    const float* bu = (const float*)d_in[9];
    const float* Wf = (const float*)d_in[10];
    const float* bf = (const float*)d_in[11];
    float* out = (float*)d_out;

    char* ws = (char*)d_ws;
    const size_t MB = 1024 * 1024;
    int*   cols  = (int*)  (ws);                    // 4 MB (upper lists)
    int*   cols2 = (int*)  (ws + 4 * MB);           // 4 MB (mirror lists)
    int*   degU  = (int*)  (ws + 8 * MB);           // 32 KB
    int*   cnt2  = (int*)  (ws + 8 * MB + 65536);   // 32 KB
    float* T0    = (float*)(ws + 9  * MB);          // 4 MB fp32
    uint*  P1    = (uint*) (ws + 13 * MB);          // 2 MB bf16
    uint*  T2    = (uint*) (ws + 15 * MB);          // 2 MB bf16
    float* T3    = (float*)(ws + 17 * MB);          // 512 KB fp32
    float* sraw  = (float*)(ws + 18 * MB);          // 32 KB
    int*   sel   = (int*)  (ws + 18 * MB + 65536);  // 32 KB
    float* g     = (float*)(ws + 18 * MB + 131072); // 32 KB

    // 0. zero mirror counters (32 KB)
    hipMemsetAsync(cnt2, 0, N_NODES * sizeof(int), stream);
    // 1. balanced pair-scan CSR + inline mirror  ||  t0 = x@W0+b0
    csrp_gemm0<<<512 * 9, 256, 0, stream>>>(A, cols, cols2, degU, cnt2, x, W0, b0, T0);
    // 2. h0 = relu(norm_adj(A)@t0); raw score; P1 = h0@W1 (bf16)
    spmm_score_p1<<<N_NODES / 2, 128, 0, stream>>>(T0, cols, cols2, degU, cnt2,
                                                   pw, pb, W1, P1, sraw);
    // 3. top-k radix select -> sel, g
    topk_radix<<<1, 256, 0, stream>>>(sraw, sel, g);
    // 4. xu = scatter(relu(norm_adj(Ap)@(g.P1+b1))); t2 = xu@Wu + bu (bf16)
    pool_gemm<<<N_NODES, 64, 0, stream>>>(P1, cols, cols2, degU, cnt2, sel, g,
                                          b1, Wu, bu, T2);
    // 5. hu = relu(norm_adj(A)@t2); t3 = hu@Wf + bf (fp32)
    up_gemm16<<<N_NODES, 64, 0, stream>>>(T2, cols, cols2, degU, cnt2, Wf, bf, T3);
    // 6. hf = norm_adj(A)@t3; out = log_softmax(hf)
    spmm16_lsm<<<N_NODES / 4, 64, 0, stream>>>(T3, cols, cols2, degU, cnt2, out);
}